// Round 2
// baseline (708.045 us; speedup 1.0000x reference)
//
#include <hip/hip_runtime.h>
#include <hip/hip_bf16.h>

// out[65536,1800] = ReLU(A[65536,72] @ W[1800,72]^T + b)
// A = x viewed flat: chunk c = 72 contiguous floats.
// Design: W-register-stationary. Each block owns one 64-col tile of W
// (12 bf16x8 fragments in regs) and streams 16 M-tiles with no barriers.

typedef __bf16 bf16;
typedef bf16  bf16x4 __attribute__((ext_vector_type(4)));
typedef bf16  bf16x8 __attribute__((ext_vector_type(8)));
typedef float f32x4  __attribute__((ext_vector_type(4)));

#define KDIM   72
#define NDIM   1800
#define MTILES 1024   // 65536 chunks / 64 rows per tile
#define NSEG   64     // M-segments -> grid = 29 x 64 = 1856 blocks, 16 iters each

__global__ __launch_bounds__(256, 4)
void edges_mlp_kernel(const float* __restrict__ A,    // [65536][72]
                      const float* __restrict__ W,    // [1800][72]
                      const float* __restrict__ bias, // [1800]
                      float* __restrict__ out)        // [65536][1800]
{
    __shared__ bf16 Bs[64][104];   // stride 104 bf16 = 52 words: conflict-light

    const int t  = threadIdx.x;
    const int n0 = blockIdx.x * 64;

    // ---- one-time: stage W tile -> LDS bf16, zero-pad K [72,96) ----
    for (int idx = t; idx < 64 * 3; idx += 256) {
        int r = idx / 3, p = idx % 3;
        *(uint4*)((char*)&Bs[r][0] + KDIM * 2 + p * 16) = make_uint4(0u, 0u, 0u, 0u);
    }
    for (int i = t; i < 64 * 18; i += 256) {
        int n = i / 18, q = i % 18;
        int gn = n0 + n;
        float4 v = make_float4(0.f, 0.f, 0.f, 0.f);
        if (gn < NDIM) v = *(const float4*)(W + (size_t)gn * KDIM + q * 4);
        bf16x4 h = { (bf16)v.x, (bf16)v.y, (bf16)v.z, (bf16)v.w };
        *(bf16x4*)&Bs[n][q * 4] = h;
    }
    __syncthreads();

    const int wave = t >> 6;
    const int lane = t & 63;
    const int lrow = lane & 15;   // A-row / B-col selector within fragment
    const int hi   = lane >> 4;   // k-subgroup

    // ---- one-time: B fragments + bias -> registers ----
    bf16x8 bfrag[3][4];
    #pragma unroll
    for (int ks = 0; ks < 3; ++ks)
        #pragma unroll
        for (int nt = 0; nt < 4; ++nt)
            bfrag[ks][nt] = *(const bf16x8*)&Bs[nt * 16 + lrow][ks * 32 + hi * 8];

    float bv[4];
    #pragma unroll
    for (int nt = 0; nt < 4; ++nt) {
        int col = n0 + nt * 16 + lrow;
        bv[nt] = (col < NDIM) ? bias[col] : 0.f;
    }

    const int arow_in_tile = wave * 16 + lrow;   // which of the 64 tile rows this lane loads

    // ---- barrier-free M loop: 16 independent tiles per block ----
    for (int mt = blockIdx.y; mt < MTILES; mt += NSEG) {
        const size_t m0 = (size_t)mt * 64;
        const float* arow = A + (m0 + arow_in_tile) * KDIM;

        // A fragments: direct global->reg, fp32 -> bf16. k>=72 is zero.
        bf16x8 afrag[3];
        #pragma unroll
        for (int ks = 0; ks < 3; ++ks) {
            const int k0 = ks * 32 + hi * 8;
            float av[8];
            if (k0 < KDIM) {   // ks<2 always; ks==2 only hi==0 (k 64..71)
                float4 u0 = *(const float4*)(arow + k0);
                float4 u1 = *(const float4*)(arow + k0 + 4);
                av[0] = u0.x; av[1] = u0.y; av[2] = u0.z; av[3] = u0.w;
                av[4] = u1.x; av[5] = u1.y; av[6] = u1.z; av[7] = u1.w;
            } else {
                #pragma unroll
                for (int j = 0; j < 8; ++j) av[j] = 0.f;
            }
            bf16x8 h;
            #pragma unroll
            for (int j = 0; j < 8; ++j) h[j] = (bf16)av[j];
            afrag[ks] = h;
        }

        f32x4 acc[4] = { {0,0,0,0}, {0,0,0,0}, {0,0,0,0}, {0,0,0,0} };
        #pragma unroll
        for (int ks = 0; ks < 3; ++ks)
            #pragma unroll
            for (int nt = 0; nt < 4; ++nt)
                acc[nt] = __builtin_amdgcn_mfma_f32_16x16x32_bf16(afrag[ks], bfrag[ks][nt], acc[nt], 0, 0, 0);

        // epilogue: D layout lane l, reg r -> row=(l>>4)*4+r, col=l&15
        const size_t orow0 = m0 + wave * 16 + hi * 4;
        #pragma unroll
        for (int nt = 0; nt < 4; ++nt) {
            int col = n0 + nt * 16 + lrow;
            if (col < NDIM) {
                #pragma unroll
                for (int r = 0; r < 4; ++r) {
                    float v = fmaxf(acc[nt][r] + bv[nt], 0.0f);
                    __builtin_nontemporal_store(v, &out[(orow0 + r) * NDIM + col]);
                }
            }
        }
    }
}

extern "C" void kernel_launch(void* const* d_in, const int* in_sizes, int n_in,
                              void* d_out, int out_size, void* d_ws, size_t ws_size,
                              hipStream_t stream) {
    const float* x = (const float*)d_in[0];
    const float* W = (const float*)d_in[1];
    const float* b = (const float*)d_in[2];
    float* out = (float*)d_out;

    dim3 grid((NDIM + 63) / 64, NSEG);   // (29, 64)
    edges_mlp_kernel<<<grid, 256, 0, stream>>>(x, W, b, out);
}

// Round 3
// 619.519 us; speedup vs baseline: 1.1429x; 1.1429x over previous
//
#include <hip/hip_runtime.h>
#include <hip/hip_bf16.h>

// out[65536,1800] = ReLU(A[65536,72] @ W[1800,72]^T + b)
// M-stationary: each wave owns 16 M-rows across ALL N -> every output cache
// line written by one block (one L2), full-line writes, no seams.
// W pre-swizzled to bf16 fragment order in d_ws by a pre-kernel.

typedef __bf16 bf16;
typedef bf16  bf16x8 __attribute__((ext_vector_type(8)));
typedef float f32x4  __attribute__((ext_vector_type(4)));

#define KDIM    72
#define NDIM    1800
#define NCHUNK  29              // ceil(1800/64)
#define NFRAG   (NCHUNK * 4)    // 116 16-col fragments (incl. zero pad)
#define WB_BYTES (NFRAG * 3 * 64 * 8 * 2)   // 356352
#define BIAS_OFF WB_BYTES                   // 16B-aligned
#define NPAD    1856

// ---- pre-kernel: W[1800][72] fp32 -> fragment-ordered bf16 [nfrag][ks][lane][8]
__global__ void swizzle_W_kernel(const float* __restrict__ W, bf16* __restrict__ Wb) {
    int idx = blockIdx.x * 256 + threadIdx.x;          // one thread per 8-elem frag slice
    if (idx >= NFRAG * 3 * 64) return;
    int lane = idx & 63;
    int ks   = (idx >> 6) % 3;
    int frag = idx / 192;
    int n  = frag * 16 + (lane & 15);
    int k0 = ks * 32 + (lane >> 4) * 8;
    bf16x8 h = {0,0,0,0,0,0,0,0};
    if (n < NDIM && k0 < KDIM) {                       // k0<72 => all 8 k valid
        const float* p = W + (size_t)n * KDIM + k0;
        float4 u0 = *(const float4*)p;
        float4 u1 = *(const float4*)(p + 4);
        h[0]=(bf16)u0.x; h[1]=(bf16)u0.y; h[2]=(bf16)u0.z; h[3]=(bf16)u0.w;
        h[4]=(bf16)u1.x; h[5]=(bf16)u1.y; h[6]=(bf16)u1.z; h[7]=(bf16)u1.w;
    }
    *((bf16x8*)Wb + idx) = h;
}

__global__ void pad_bias_kernel(const float* __restrict__ b, float* __restrict__ bp) {
    int i = blockIdx.x * 256 + threadIdx.x;
    if (i < NPAD) bp[i] = (i < NDIM) ? b[i] : 0.f;
}

__global__ __launch_bounds__(256, 4)
void edges_mlp_kernel(const float* __restrict__ A,     // [65536][72]
                      const bf16*  __restrict__ Wb,    // fragment-ordered
                      const float* __restrict__ biasp, // [1856] padded
                      float* __restrict__ out)         // [65536][1800]
{
    const int t    = threadIdx.x;
    const int wave = t >> 6;
    const int lane = t & 63;
    const int hi   = lane >> 4;

    // this lane's M row (D "col" = lane&15 under swapped operands)
    const size_t m = (size_t)blockIdx.x * 64 + wave * 16 + (lane & 15);

    // ---- A fragments once: lane holds A[m][k], k in [ks*32+hi*8, +8) ----
    const float* arow = A + m * KDIM;
    bf16x8 afrag[3];
    #pragma unroll
    for (int ks = 0; ks < 3; ++ks) {
        const int k0 = ks * 32 + hi * 8;
        bf16x8 h = {0,0,0,0,0,0,0,0};
        if (k0 < KDIM) {
            float4 u0 = *(const float4*)(arow + k0);
            float4 u1 = *(const float4*)(arow + k0 + 4);
            h[0]=(bf16)u0.x; h[1]=(bf16)u0.y; h[2]=(bf16)u0.z; h[3]=(bf16)u0.w;
            h[4]=(bf16)u1.x; h[5]=(bf16)u1.y; h[6]=(bf16)u1.z; h[7]=(bf16)u1.w;
        }
        afrag[ks] = h;
    }

    const bf16x8* wp = (const bf16x8*)Wb + lane;   // + ((frag*3+ks)*64)
    float* orow = out + m * NDIM;

    for (int nc = 0; nc < NCHUNK; ++nc) {
        // ---- 12 W fragments: one coalesced dwordx4 each (L2-resident) ----
        bf16x8 wfr[3][4];
        #pragma unroll
        for (int nt = 0; nt < 4; ++nt)
            #pragma unroll
            for (int ks = 0; ks < 3; ++ks)
                wfr[ks][nt] = wp[((size_t)(nc * 4 + nt) * 3 + ks) * 64];

        f32x4 acc[4] = { {0,0,0,0}, {0,0,0,0}, {0,0,0,0}, {0,0,0,0} };
        #pragma unroll
        for (int ks = 0; ks < 3; ++ks)
            #pragma unroll
            for (int nt = 0; nt < 4; ++nt)   // swapped: D col = M, D row = N
                acc[nt] = __builtin_amdgcn_mfma_f32_16x16x32_bf16(wfr[ks][nt], afrag[ks], acc[nt], 0, 0, 0);

        // ---- epilogue: lane has 4 consecutive N -> float4 store ----
        const int nb = nc * 64 + hi * 4;
        #pragma unroll
        for (int nt = 0; nt < 4; ++nt) {
            int n = nb + nt * 16;
            if (n + 3 < NDIM) {
                float4 bb = *(const float4*)(biasp + n);
                float4 v;
                v.x = fmaxf(acc[nt][0] + bb.x, 0.f);
                v.y = fmaxf(acc[nt][1] + bb.y, 0.f);
                v.z = fmaxf(acc[nt][2] + bb.z, 0.f);
                v.w = fmaxf(acc[nt][3] + bb.w, 0.f);
                *(float4*)(orow + n) = v;
            }
        }
    }
}

extern "C" void kernel_launch(void* const* d_in, const int* in_sizes, int n_in,
                              void* d_out, int out_size, void* d_ws, size_t ws_size,
                              hipStream_t stream) {
    const float* x = (const float*)d_in[0];
    const float* W = (const float*)d_in[1];
    const float* b = (const float*)d_in[2];
    float* out = (float*)d_out;

    bf16*  Wb    = (bf16*)d_ws;
    float* biasp = (float*)((char*)d_ws + BIAS_OFF);

    swizzle_W_kernel<<<(NFRAG * 3 * 64 + 255) / 256, 256, 0, stream>>>(W, Wb);
    pad_bias_kernel<<<(NPAD + 255) / 256, 256, 0, stream>>>(b, biasp);

    const int chunks = in_sizes[0] / KDIM;   // 65536
    edges_mlp_kernel<<<chunks / 64, 256, 0, stream>>>(x, Wb, biasp, out);
}